// Round 8
// baseline (41.534 us; speedup 1.0000x reference)
//
#include <hip/hip_runtime.h>

typedef float v4f __attribute__((ext_vector_type(4)));

#define BLK 256
#define IPT 4                 // i-particles per thread
#define TI (BLK * IPT)        // 1024 i's per block
#define TJ 64                 // j's staged per block
#define G_CONST 0.001f
#define EPS_CONST 1e-6f

// Full N^2, expansion form: r^2 = (si+eps) + sj + xi*(-2xj) + yi*(-2yj) + zi*(-2zj)
// -> 5 scalar VALU + 1 rsq per pair (diff form was 7+1). Packed fp32 buys
// nothing on gfx950 (157 TF peak = scalar v_fma rate), so all-scalar for
// scheduler freedom and lean VGPR. 2048 blocks + <=64 VGPR -> 8 waves/SIMD.
__global__ __launch_bounds__(BLK, 8)
void grav_kernel(const float* __restrict__ q, const float* __restrict__ m,
                 float* __restrict__ out, int N) {
  const int b   = blockIdx.z;
  const int tid = threadIdx.x;
  const int j0  = blockIdx.y * TJ;
  const int i0  = blockIdx.x * TI;

  __shared__ float txs[TJ], tys[TJ], tzs[TJ], ssj[TJ], msj[TJ];
  __shared__ float wsum[4];

  const float* qb = q + (size_t)b * N * 3;

  // Stage j tile: -2*coords, |qj|^2, mj (SoA -> broadcast ds_read_b128).
  if (tid < TJ) {
    const int j = j0 + tid;
    const float x = qb[3 * j + 0];
    const float y = qb[3 * j + 1];
    const float z = qb[3 * j + 2];
    txs[tid] = -2.f * x;
    tys[tid] = -2.f * y;
    tzs[tid] = -2.f * z;
    ssj[tid] = fmaf(x, x, fmaf(y, y, z * z));
    msj[tid] = m[j];
  }

  // Per-thread i-slots: coords, |qi|^2+eps, mass (5 regs/slot).
  float xi[IPT], yi[IPT], zi[IPT], se[IPT], mi[IPT];
#pragma unroll
  for (int s = 0; s < IPT; ++s) {
    const int i = i0 + s * BLK + tid;
    xi[s] = qb[3 * i + 0];
    yi[s] = qb[3 * i + 1];
    zi[s] = qb[3 * i + 2];
    se[s] = fmaf(xi[s], xi[s], fmaf(yi[s], yi[s], fmaf(zi[s], zi[s], EPS_CONST)));
    mi[s] = m[i];
  }

  __syncthreads();

  float acc[IPT] = {0.f, 0.f, 0.f, 0.f};
  // Does this block's j-tile overlap its i-range? (block-uniform)
  const bool diag = (j0 >= i0) && (j0 < i0 + TI);

  if (diag) {
#pragma unroll 2
    for (int k = 0; k < TJ; k += 4) {
      const v4f tx = *(const v4f*)&txs[k];
      const v4f ty = *(const v4f*)&tys[k];
      const v4f tz = *(const v4f*)&tzs[k];
      const v4f sj = *(const v4f*)&ssj[k];
      const v4f mj = *(const v4f*)&msj[k];
#pragma unroll
      for (int s = 0; s < IPT; ++s) {
        const int i = i0 + s * BLK + tid;
#pragma unroll
        for (int u = 0; u < 4; ++u) {
          float t = se[s] + sj[u];
          t = fmaf(xi[s], tx[u], t);
          t = fmaf(yi[s], ty[u], t);
          t = fmaf(zi[s], tz[u], t);
          float ri = __builtin_amdgcn_rsqf(t);
          // Self pair: r2 = eps +/- rounding (can be negative -> NaN);
          // mask to 0 exactly like the reference's diagonal zeroing.
          ri = (i == j0 + k + u) ? 0.f : ri;
          acc[s] = fmaf(mj[u], ri, acc[s]);
        }
      }
    }
  } else {
#pragma unroll 2
    for (int k = 0; k < TJ; k += 4) {
      const v4f tx = *(const v4f*)&txs[k];
      const v4f ty = *(const v4f*)&tys[k];
      const v4f tz = *(const v4f*)&tzs[k];
      const v4f sj = *(const v4f*)&ssj[k];
      const v4f mj = *(const v4f*)&msj[k];
#pragma unroll
      for (int s = 0; s < IPT; ++s) {
#pragma unroll
        for (int u = 0; u < 4; ++u) {
          float t = se[s] + sj[u];
          t = fmaf(xi[s], tx[u], t);
          t = fmaf(yi[s], ty[u], t);
          t = fmaf(zi[s], tz[u], t);
          acc[s] = fmaf(mj[u], __builtin_amdgcn_rsqf(t), acc[s]);
        }
      }
    }
  }

  float tsum = 0.f;
#pragma unroll
  for (int s = 0; s < IPT; ++s) tsum += mi[s] * acc[s];

  // Block reduction: 64-lane shuffle, then across 4 waves via LDS.
#pragma unroll
  for (int off = 32; off > 0; off >>= 1) tsum += __shfl_down(tsum, off);
  const int wid  = tid >> 6;
  const int lane = tid & 63;
  if (lane == 0) wsum[wid] = tsum;
  __syncthreads();
  if (tid == 0) {
    const float s = (wsum[0] + wsum[1]) + (wsum[2] + wsum[3]);
    atomicAdd(out + b, s * (-0.5f * G_CONST));
  }
}

extern "C" void kernel_launch(void* const* d_in, const int* in_sizes, int n_in,
                              void* d_out, int out_size, void* d_ws, size_t ws_size,
                              hipStream_t stream) {
  const float* q = (const float*)d_in[0];
  const float* m = (const float*)d_in[1];
  float* out = (float*)d_out;

  const int N = in_sizes[1];
  const int B = in_sizes[0] / (N * 3);

  hipMemsetAsync(out, 0, (size_t)out_size * sizeof(float), stream);

  dim3 grid(N / TI, N / TJ, B);   // 4 x 64 x 8 = 2048 blocks
  grav_kernel<<<grid, BLK, 0, stream>>>(q, m, out, N);
}

// Round 9
// 31.293 us; speedup vs baseline: 1.3273x; 1.3273x over previous
//
#include <hip/hip_runtime.h>

typedef float v4f __attribute__((ext_vector_type(4)));

#define BLK 256
#define IPT 4                 // i-particles per thread
#define TI (BLK * IPT)        // 1024 i's per block
#define TJ 64                 // j's staged per block
#define JBT (TI / TJ)         // 16 j-blocks per i-tile
#define G_CONST 0.001f
#define EPS_CONST 1e-6f

// Triangular at (1024 x 64) block granularity: 62.5% of full-N^2 work.
//  - off-diag blocks (j-tile strictly below i-tile): each unordered pair once, weight 1
//  - diag blocks (j-tile inside i-tile): full rectangle, self masked per-pair, weight 0.5
// Expansion form r^2 = (si+eps) + sj + xi*(-2xj) + yi*(-2yj) + zi*(-2zj):
// 5 VALU + 1 rsq (+1 acc fma) per pair, all scalar (pk fp32 is half-rate on gfx950).
// bounds(256,4): <=128 VGPR, no spills (R8's bounds(256,8) spilled and masked the gain).
__global__ __launch_bounds__(BLK, 4)
void grav_kernel(const float* __restrict__ q, const float* __restrict__ m,
                 float* __restrict__ out, int N) {
  const int b   = blockIdx.z;
  const int tid = threadIdx.x;

  // Decode blockIdx.x -> (i-tile a, j-block jt) in the triangular layout:
  // i-tile a owns JBT*(a+1) j-blocks (16a off-diag + 16 diag). <=4 scalar iters.
  int rel = blockIdx.x;
  int a = 0;
  while (rel >= JBT * (a + 1)) { rel -= JBT * (a + 1); ++a; }
  const int jt   = rel;
  const bool diag = (jt >= JBT * a);   // j-tile inside i-range?
  const int i0 = a * TI;
  const int j0 = jt * TJ;

  __shared__ float txs[TJ], tys[TJ], tzs[TJ], ssj[TJ], msj[TJ];
  __shared__ float wsum[4];

  const float* qb = q + (size_t)b * N * 3;

  // Stage j tile: -2*coords, |qj|^2, mj (SoA -> broadcast ds_read_b128).
  if (tid < TJ) {
    const int j = j0 + tid;
    const float x = qb[3 * j + 0];
    const float y = qb[3 * j + 1];
    const float z = qb[3 * j + 2];
    txs[tid] = -2.f * x;
    tys[tid] = -2.f * y;
    tzs[tid] = -2.f * z;
    ssj[tid] = fmaf(x, x, fmaf(y, y, z * z));
    msj[tid] = m[j];
  }

  // Per-thread i-slots: coords, |qi|^2+eps, mass.
  float xi[IPT], yi[IPT], zi[IPT], se[IPT], mi[IPT];
#pragma unroll
  for (int s = 0; s < IPT; ++s) {
    const int i = i0 + s * BLK + tid;
    xi[s] = qb[3 * i + 0];
    yi[s] = qb[3 * i + 1];
    zi[s] = qb[3 * i + 2];
    se[s] = fmaf(xi[s], xi[s], fmaf(yi[s], yi[s], fmaf(zi[s], zi[s], EPS_CONST)));
    mi[s] = m[i];
  }

  __syncthreads();

  float acc[IPT] = {0.f, 0.f, 0.f, 0.f};

  if (diag) {
    for (int k = 0; k < TJ; k += 4) {
      const v4f tx = *(const v4f*)&txs[k];
      const v4f ty = *(const v4f*)&tys[k];
      const v4f tz = *(const v4f*)&tzs[k];
      const v4f sj = *(const v4f*)&ssj[k];
      const v4f mj = *(const v4f*)&msj[k];
#pragma unroll
      for (int s = 0; s < IPT; ++s) {
        const int i = i0 + s * BLK + tid;
#pragma unroll
        for (int u = 0; u < 4; ++u) {
          float t = se[s] + sj[u];
          t = fmaf(xi[s], tx[u], t);
          t = fmaf(yi[s], ty[u], t);
          t = fmaf(zi[s], tz[u], t);
          float ri = __builtin_amdgcn_rsqf(t);
          // self pair: t = eps +/- rounding (may be <=0 -> NaN); mask in-loop
          ri = (i == j0 + k + u) ? 0.f : ri;
          acc[s] = fmaf(mj[u], ri, acc[s]);
        }
      }
    }
  } else {
    for (int k = 0; k < TJ; k += 4) {
      const v4f tx = *(const v4f*)&txs[k];
      const v4f ty = *(const v4f*)&tys[k];
      const v4f tz = *(const v4f*)&tzs[k];
      const v4f sj = *(const v4f*)&ssj[k];
      const v4f mj = *(const v4f*)&msj[k];
#pragma unroll
      for (int s = 0; s < IPT; ++s) {
#pragma unroll
        for (int u = 0; u < 4; ++u) {
          float t = se[s] + sj[u];
          t = fmaf(xi[s], tx[u], t);
          t = fmaf(yi[s], ty[u], t);
          t = fmaf(zi[s], tz[u], t);
          acc[s] = fmaf(mj[u], __builtin_amdgcn_rsqf(t), acc[s]);
        }
      }
    }
  }

  float tsum = 0.f;
#pragma unroll
  for (int s = 0; s < IPT; ++s) tsum += mi[s] * acc[s];

  // Block reduction: 64-lane shuffle, then across 4 waves via LDS.
#pragma unroll
  for (int off = 32; off > 0; off >>= 1) tsum += __shfl_down(tsum, off);
  const int wid  = tid >> 6;
  const int lane = tid & 63;
  if (lane == 0) wsum[wid] = tsum;
  __syncthreads();
  if (tid == 0) {
    const float s = (wsum[0] + wsum[1]) + (wsum[2] + wsum[3]);
    // off-diag blocks cover each unordered pair once -> weight 1 (i.e. -G);
    // diag blocks cover both orders -> weight 1/2 (matches reference's /2).
    const float scale = diag ? (-0.5f * G_CONST) : (-G_CONST);
    atomicAdd(out + b, s * scale);
  }
}

extern "C" void kernel_launch(void* const* d_in, const int* in_sizes, int n_in,
                              void* d_out, int out_size, void* d_ws, size_t ws_size,
                              hipStream_t stream) {
  const float* q = (const float*)d_in[0];
  const float* m = (const float*)d_in[1];
  float* out = (float*)d_out;

  const int N = in_sizes[1];
  const int B = in_sizes[0] / (N * 3);

  hipMemsetAsync(out, 0, (size_t)out_size * sizeof(float), stream);

  const int nti = N / TI;                      // 4 i-tiles
  const int bpb = JBT * nti * (nti + 1) / 2;   // 160 blocks per batch
  dim3 grid(bpb, 1, B);                        // 1280 blocks
  grav_kernel<<<grid, BLK, 0, stream>>>(q, m, out, N);
}